// Round 1
// baseline (18660.770 us; speedup 1.0000x reference)
//
#include <hip/hip_runtime.h>
#include <hip/hip_bf16.h>
#include <hip/hip_cooperative_groups.h>

namespace cg = cooperative_groups;

typedef __attribute__((ext_vector_type(8))) short  short8;   // 8 bf16 (4 VGPRs) MFMA frag
typedef __attribute__((ext_vector_type(4))) float  f32x4;    // MFMA accum frag

#define T_TOTAL 512
#define BATCH   64
#define EMB     512
#define RNN     1024
#define G3      3072      // 3*RNN
#define TCH     128       // timesteps per chunk (ws: 128*64*3072*2B = 50.3 MB)
#define NCHUNK  4
#define WPAD    1032      // LDS row stride for w_hh slice (1024+8: b128 reads 2-way = free)

// ---- bf16 helpers (avoid __hip_bfloat16 class in __shared__) ----
__device__ __forceinline__ unsigned short f2bf(float f) {
    union { float f; unsigned int u; } v; v.f = f;
    unsigned int r = v.u + 0x7fffu + ((v.u >> 16) & 1u);   // round-nearest-even
    return (unsigned short)(r >> 16);
}
__device__ __forceinline__ float bf2f(unsigned short h) {
    union { unsigned int u; float f; } v; v.u = ((unsigned int)h) << 16;
    return v.f;
}
__device__ __forceinline__ float sigmoidf_(float x) { return 1.f / (1.f + __expf(-x)); }
__device__ __forceinline__ float tanhf_(float x) {
    float ax = fabsf(x);
    float e2 = __expf(-2.f * ax);
    float t  = (1.f - e2) / (1.f + e2);
    return x < 0.f ? -t : t;
}

// ============================================================================
// K1: gi[t,b,:] = emb_table[x[t,b]] @ w_ih^T + b_ih   (one chunk of TCH steps)
// 64x64 tile per WG, 4 waves of 32x32, 16x16x32 bf16 MFMA, K=512.
// A row gather (embedding) fused into staging. Output bf16.
// ============================================================================
__global__ __launch_bounds__(256) void gi_kernel(
    const int* __restrict__ x, const float* __restrict__ emb,
    const float* __restrict__ w_ih, const float* __restrict__ b_ih,
    unsigned short* __restrict__ gi, int t0)
{
    __shared__ __align__(16) unsigned short Asm[64 * 40];  // 64 rows x 32 bf16, pad->40
    __shared__ __align__(16) unsigned short Bsm[64 * 40];

    const int tid = threadIdx.x;
    const int mt = blockIdx.x & 127;        // 8192/64 m-tiles
    const int nt = blockIdx.x >> 7;         // 3072/64 n-tiles
    const int m0 = mt * 64, n0 = nt * 64;

    // staging assignment: thread -> (row r, 8-float k segment)
    const int r  = tid >> 2;
    const int c8 = (tid & 3) * 8;
    const int xi = x[t0 * BATCH + m0 + r];              // global (t,b) row index
    const float* arow = emb  + (size_t)xi * EMB;
    const float* brow = w_ih + (size_t)(n0 + r) * EMB;

    const int lane = tid & 63, wv = tid >> 6;
    const int m_off = (wv & 1) * 32, n_off = (wv >> 1) * 32;
    const int lr = lane & 15, lq = lane >> 4;

    f32x4 acc[2][2];
    #pragma unroll
    for (int i = 0; i < 2; ++i)
        #pragma unroll
        for (int j = 0; j < 2; ++j) acc[i][j] = (f32x4){0.f, 0.f, 0.f, 0.f};

    for (int k0 = 0; k0 < EMB; k0 += 32) {
        const float4 a0 = *(const float4*)(arow + k0 + c8);
        const float4 a1 = *(const float4*)(arow + k0 + c8 + 4);
        const float4 b0 = *(const float4*)(brow + k0 + c8);
        const float4 b1 = *(const float4*)(brow + k0 + c8 + 4);
        __syncthreads();  // previous iter's frag reads done
        short8 av, bv;
        av[0]=f2bf(a0.x); av[1]=f2bf(a0.y); av[2]=f2bf(a0.z); av[3]=f2bf(a0.w);
        av[4]=f2bf(a1.x); av[5]=f2bf(a1.y); av[6]=f2bf(a1.z); av[7]=f2bf(a1.w);
        bv[0]=f2bf(b0.x); bv[1]=f2bf(b0.y); bv[2]=f2bf(b0.z); bv[3]=f2bf(b0.w);
        bv[4]=f2bf(b1.x); bv[5]=f2bf(b1.y); bv[6]=f2bf(b1.z); bv[7]=f2bf(b1.w);
        *(short8*)&Asm[r * 40 + c8] = av;
        *(short8*)&Bsm[r * 40 + c8] = bv;
        __syncthreads();

        const short8 fa0 = *(const short8*)&Asm[(m_off + lr)      * 40 + lq * 8];
        const short8 fa1 = *(const short8*)&Asm[(m_off + 16 + lr) * 40 + lq * 8];
        const short8 fb0 = *(const short8*)&Bsm[(n_off + lr)      * 40 + lq * 8];
        const short8 fb1 = *(const short8*)&Bsm[(n_off + 16 + lr) * 40 + lq * 8];
        acc[0][0] = __builtin_amdgcn_mfma_f32_16x16x32_bf16(fa0, fb0, acc[0][0], 0, 0, 0);
        acc[0][1] = __builtin_amdgcn_mfma_f32_16x16x32_bf16(fa0, fb1, acc[0][1], 0, 0, 0);
        acc[1][0] = __builtin_amdgcn_mfma_f32_16x16x32_bf16(fa1, fb0, acc[1][0], 0, 0, 0);
        acc[1][1] = __builtin_amdgcn_mfma_f32_16x16x32_bf16(fa1, fb1, acc[1][1], 0, 0, 0);
    }

    const float bia0 = b_ih[n0 + n_off + lr];
    const float bia1 = b_ih[n0 + n_off + 16 + lr];
    #pragma unroll
    for (int mi = 0; mi < 2; ++mi)
        #pragma unroll
        for (int ni = 0; ni < 2; ++ni) {
            const int n = n0 + n_off + ni * 16 + lr;
            const float bia = ni ? bia1 : bia0;
            #pragma unroll
            for (int q = 0; q < 4; ++q) {
                const int m = m0 + m_off + mi * 16 + lq * 4 + q;  // C: row=(lane>>4)*4+reg
                gi[(size_t)m * G3 + n] = f2bf(acc[mi][ni][q] + bia);
            }
        }
}

// ============================================================================
// K2: the recurrence (cooperative, 256 WGs x 256 thr, one per CU).
// WG (g,s): batches b0=g*32..+32, units j0=s*8..+8 -> 24 rows of w_hh,
// persistent in LDS as bf16 for all TCH steps. One grid.sync per step,
// h ping-pong (bf16) in global ws; per-thread f32 h state in registers.
// ============================================================================
__global__ __launch_bounds__(256, 1) void rec_kernel(
    const unsigned short* __restrict__ gi,
    const float* __restrict__ w_hh, const float* __restrict__ b_hh,
    unsigned short* __restrict__ hb0, unsigned short* __restrict__ hb1,
    float* __restrict__ hf, int chunk)
{
    __shared__ __align__(16) unsigned short Wsm[24 * WPAD];  // 48.4 KB
    __shared__ float red[32 * 33];                            // gh handoff, padded

    cg::grid_group grid = cg::this_grid();
    const int tid = threadIdx.x;
    const int wg  = blockIdx.x;
    const int g = wg & 1, s = wg >> 1;      // 2 batch groups x 128 unit slices
    const int b0 = g * 32, j0 = s * 8;

    // ---- load w_hh slice -> LDS bf16 (rows: [gate*8+u][k]) ----
    #pragma unroll 4
    for (int it = 0; it < 24; ++it) {
        const int i   = it * 256 + tid;
        const int row = i >> 8;             // 0..23
        const int c4  = (i & 255) * 4;
        const int gate = row >> 3, u = row & 7;
        const float4 v = *(const float4*)(w_hh + (size_t)(gate * RNN + j0 + u) * RNN + c4);
        unsigned short* dst = &Wsm[row * WPAD + c4];
        dst[0] = f2bf(v.x); dst[1] = f2bf(v.y); dst[2] = f2bf(v.z); dst[3] = f2bf(v.w);
    }

    // ---- gate-thread identity: all 256 threads own one (unit, batch) ----
    const int u  = tid & 7;
    const int bl = tid >> 3;                // 0..31
    const int j  = j0 + u;
    const int b  = b0 + bl;
    const float bhr = b_hh[j], bhi = b_hh[RNN + j], bhn = b_hh[2 * RNN + j];

    float h_reg;
    if (chunk == 0) {
        h_reg = 0.f;
        hb0[b * RNN + j] = 0;               // zero initial h (ws is poisoned)
    } else {
        h_reg = hf[b * RNN + j];            // bf16 ping buffer 0 carries over
    }
    grid.sync();

    // ---- MFMA identity ----
    const int lane = tid & 63, wv = tid >> 6;
    const int mt = wv & 1, ntile = wv >> 1;
    const int lr = lane & 15, lq = lane >> 4;
    const int ar = mt ? (lr < 8 ? 16 + lr : 23) : lr;        // clamp pad rows (24..31 unused)
    const unsigned short* wrow = Wsm + ar * WPAD;
    const size_t hrow = (size_t)(b0 + ntile * 16 + lr) * RNN;

    for (int t = 0; t < TCH; ++t) {
        const unsigned short* hrd = (t & 1) ? hb1 : hb0;
        unsigned short*       hwr = (t & 1) ? hb0 : hb1;

        // prefetch gi for this step (consumed after the MFMA phase)
        const size_t gbase = ((size_t)t * BATCH + b) * G3 + j0 + u;
        const float gir = bf2f(gi[gbase]);
        const float gii = bf2f(gi[gbase + RNN]);
        const float gin = bf2f(gi[gbase + 2 * RNN]);

        f32x4 acc = (f32x4){0.f, 0.f, 0.f, 0.f};
        #pragma unroll 8
        for (int ks = 0; ks < 32; ++ks) {
            const int k = ks * 32 + lq * 8;
            const short8 bfrag = *(const short8*)(hrd + hrow + k);
            const short8 afrag = *(const short8*)(wrow + k);
            acc = __builtin_amdgcn_mfma_f32_16x16x32_bf16(afrag, bfrag, acc, 0, 0, 0);
        }
        #pragma unroll
        for (int q = 0; q < 4; ++q)
            red[(mt * 16 + lq * 4 + q) * 33 + ntile * 16 + lr] = acc[q];
        __syncthreads();

        const float ghr = red[u * 33 + bl];
        const float ghi = red[(8 + u) * 33 + bl];
        const float ghn = red[(16 + u) * 33 + bl];
        const float rr = sigmoidf_(gir + ghr + bhr);
        const float zz = sigmoidf_(gii + ghi + bhi);
        const float nn = tanhf_(gin + rr * (ghn + bhn));
        h_reg = zz * nn + (1.f - zz) * h_reg;     // reference: z gates newgate
        hwr[b * RNN + j] = f2bf(h_reg);

        grid.sync();   // h visible grid-wide; also guards red[] reuse
    }
    hf[b * RNN + j] = h_reg;
}

// ============================================================================
// K3: out[b,o] = h_last[b,:] . fc_w[o,:] + fc_b[o]
// ============================================================================
__global__ __launch_bounds__(256) void out_kernel(
    const float* __restrict__ hf, const float* __restrict__ fc_w,
    const float* __restrict__ fc_b, float* __restrict__ out)
{
    __shared__ float red[256];
    const int bidx = blockIdx.x, tid = threadIdx.x;
    const int o = tid & 3, seg = tid >> 2;
    const float* hp = hf   + (size_t)bidx * RNN + seg * 16;
    const float* wp = fc_w + (size_t)o * RNN + seg * 16;
    float acc = 0.f;
    #pragma unroll
    for (int i = 0; i < 16; ++i) acc += hp[i] * wp[i];
    red[tid] = acc;
    __syncthreads();
    if (tid < 4) {
        float s = fc_b[tid];
        #pragma unroll 8
        for (int q = 0; q < 64; ++q) s += red[q * 4 + tid];
        out[bidx * 4 + tid] = s;
    }
}

extern "C" void kernel_launch(void* const* d_in, const int* in_sizes, int n_in,
                              void* d_out, int out_size, void* d_ws, size_t ws_size,
                              hipStream_t stream)
{
    const int*   x     = (const int*)d_in[0];
    const float* emb   = (const float*)d_in[1];
    const float* w_ih  = (const float*)d_in[2];
    const float* w_hh  = (const float*)d_in[3];
    const float* b_ih  = (const float*)d_in[4];
    const float* b_hh  = (const float*)d_in[5];
    const float* fc_w  = (const float*)d_in[6];
    const float* fc_b  = (const float*)d_in[7];
    float*       out   = (float*)d_out;

    char* ws = (char*)d_ws;
    unsigned short* gi_buf = (unsigned short*)ws;                      // 50.3 MB
    size_t off = (size_t)TCH * BATCH * G3 * 2;
    unsigned short* hb0 = (unsigned short*)(ws + off); off += BATCH * RNN * 2;
    unsigned short* hb1 = (unsigned short*)(ws + off); off += BATCH * RNN * 2;
    float*          hf  = (float*)(ws + off);

    for (int c = 0; c < NCHUNK; ++c) {
        const int t0 = c * TCH;
        gi_kernel<<<dim3(128 * 48), dim3(256), 0, stream>>>(x, emb, w_ih, b_ih, gi_buf, t0);
        void* args[7];
        args[0] = (void*)&gi_buf; args[1] = (void*)&w_hh; args[2] = (void*)&b_hh;
        args[3] = (void*)&hb0;    args[4] = (void*)&hb1;  args[5] = (void*)&hf;
        int cc = c; args[6] = (void*)&cc;
        hipLaunchCooperativeKernel((const void*)rec_kernel, dim3(256), dim3(256),
                                   args, 0, stream);
    }
    out_kernel<<<dim3(BATCH), dim3(256), 0, stream>>>(hf, fc_w, fc_b, out);
}

// Round 2
// 9075.224 us; speedup vs baseline: 2.0562x; 2.0562x over previous
//
#include <hip/hip_runtime.h>
#include <hip/hip_bf16.h>

typedef __attribute__((ext_vector_type(8))) short  short8;   // 8 bf16 (4 VGPRs) MFMA frag
typedef __attribute__((ext_vector_type(4))) float  f32x4;    // MFMA accum frag

#define T_TOTAL 512
#define BATCH   64
#define EMB     512
#define RNN     1024
#define G3      3072      // 3*RNN
#define TCH     128       // timesteps per chunk (ws: 128*64*3072*2B = 50.3 MB)
#define NCHUNK  4
#define WPAD    1032      // LDS row stride for w_hh slice (1024+8: b128 reads 2-way = free)
#define NWG     256
#define NCNT    32        // arrival counters (64B-padded): 8 WGs per counter

// ---- bf16 helpers (avoid __hip_bfloat16 class in __shared__) ----
__device__ __forceinline__ unsigned short f2bf(float f) {
    union { float f; unsigned int u; } v; v.f = f;
    unsigned int r = v.u + 0x7fffu + ((v.u >> 16) & 1u);   // round-nearest-even
    return (unsigned short)(r >> 16);
}
__device__ __forceinline__ float bf2f(unsigned short h) {
    union { unsigned int u; float f; } v; v.u = ((unsigned int)h) << 16;
    return v.f;
}
__device__ __forceinline__ float sigmoidf_(float x) { return 1.f / (1.f + __expf(-x)); }
__device__ __forceinline__ float tanhf_(float x) {
    float ax = fabsf(x);
    float e2 = __expf(-2.f * ax);
    float t  = (1.f - e2) / (1.f + e2);
    return x < 0.f ? -t : t;
}

// ============================================================================
// Custom grid barrier (requires co-residency -> launched cooperatively).
// bar[0 .. NCNT*16)   : padded arrival counters (monotonic, never reset)
// bar[NCNT*16]        : release flag (monotonic phase number)
// Per phase each WG adds 1 to cnt[wg&31]; master (wg 0) waits until
// sum == NWG*ph then publishes ph. Ordering: __syncthreads drains all waves'
// stores (implicit vmcnt(0) before s_barrier), one __threadfence per WG
// (wbl2+inv are cache-global) provides release; second fence after the spin
// provides acquire before any wave reads remote h.
// ============================================================================
__device__ __forceinline__ void gbar(unsigned int* bar, int wg, unsigned int ph) {
    __syncthreads();                                   // all waves' stores drained
    if (threadIdx.x == 0) {
        __threadfence();                               // release: wbl2 + inv
        __hip_atomic_fetch_add(&bar[(wg & (NCNT - 1)) * 16], 1u,
                               __ATOMIC_RELAXED, __HIP_MEMORY_SCOPE_AGENT);
        if (wg == 0) {
            for (;;) {
                unsigned int s = 0;
                #pragma unroll
                for (int i = 0; i < NCNT; ++i)
                    s += __hip_atomic_load(&bar[i * 16], __ATOMIC_RELAXED,
                                           __HIP_MEMORY_SCOPE_AGENT);
                if (s >= ph * (unsigned)NWG) break;
                __builtin_amdgcn_s_sleep(1);
            }
            __hip_atomic_store(&bar[NCNT * 16], ph, __ATOMIC_RELAXED,
                               __HIP_MEMORY_SCOPE_AGENT);
        } else {
            while (__hip_atomic_load(&bar[NCNT * 16], __ATOMIC_RELAXED,
                                     __HIP_MEMORY_SCOPE_AGENT) < ph)
                __builtin_amdgcn_s_sleep(1);
        }
        __threadfence();                               // acquire: invalidate L1/L2
    }
    __syncthreads();                                   // release waves into next step
}

__global__ void bar_init(unsigned int* bar) {
    if (threadIdx.x < NCNT * 16 + 16) bar[threadIdx.x] = 0;
}

// ============================================================================
// K1: gi[t,b,:] = emb_table[x[t,b]] @ w_ih^T + b_ih   (one chunk of TCH steps)
// 64x64 tile per WG, 4 waves of 32x32, 16x16x32 bf16 MFMA, K=512.
// ============================================================================
__global__ __launch_bounds__(256) void gi_kernel(
    const int* __restrict__ x, const float* __restrict__ emb,
    const float* __restrict__ w_ih, const float* __restrict__ b_ih,
    unsigned short* __restrict__ gi, int t0)
{
    __shared__ __align__(16) unsigned short Asm[64 * 40];
    __shared__ __align__(16) unsigned short Bsm[64 * 40];

    const int tid = threadIdx.x;
    const int mt = blockIdx.x & 127;
    const int nt = blockIdx.x >> 7;
    const int m0 = mt * 64, n0 = nt * 64;

    const int r  = tid >> 2;
    const int c8 = (tid & 3) * 8;
    const int xi = x[t0 * BATCH + m0 + r];
    const float* arow = emb  + (size_t)xi * EMB;
    const float* brow = w_ih + (size_t)(n0 + r) * EMB;

    const int lane = tid & 63, wv = tid >> 6;
    const int m_off = (wv & 1) * 32, n_off = (wv >> 1) * 32;
    const int lr = lane & 15, lq = lane >> 4;

    f32x4 acc[2][2];
    #pragma unroll
    for (int i = 0; i < 2; ++i)
        #pragma unroll
        for (int j = 0; j < 2; ++j) acc[i][j] = (f32x4){0.f, 0.f, 0.f, 0.f};

    for (int k0 = 0; k0 < EMB; k0 += 32) {
        const float4 a0 = *(const float4*)(arow + k0 + c8);
        const float4 a1 = *(const float4*)(arow + k0 + c8 + 4);
        const float4 b0 = *(const float4*)(brow + k0 + c8);
        const float4 b1 = *(const float4*)(brow + k0 + c8 + 4);
        __syncthreads();
        short8 av, bv;
        av[0]=f2bf(a0.x); av[1]=f2bf(a0.y); av[2]=f2bf(a0.z); av[3]=f2bf(a0.w);
        av[4]=f2bf(a1.x); av[5]=f2bf(a1.y); av[6]=f2bf(a1.z); av[7]=f2bf(a1.w);
        bv[0]=f2bf(b0.x); bv[1]=f2bf(b0.y); bv[2]=f2bf(b0.z); bv[3]=f2bf(b0.w);
        bv[4]=f2bf(b1.x); bv[5]=f2bf(b1.y); bv[6]=f2bf(b1.z); bv[7]=f2bf(b1.w);
        *(short8*)&Asm[r * 40 + c8] = av;
        *(short8*)&Bsm[r * 40 + c8] = bv;
        __syncthreads();

        const short8 fa0 = *(const short8*)&Asm[(m_off + lr)      * 40 + lq * 8];
        const short8 fa1 = *(const short8*)&Asm[(m_off + 16 + lr) * 40 + lq * 8];
        const short8 fb0 = *(const short8*)&Bsm[(n_off + lr)      * 40 + lq * 8];
        const short8 fb1 = *(const short8*)&Bsm[(n_off + 16 + lr) * 40 + lq * 8];
        acc[0][0] = __builtin_amdgcn_mfma_f32_16x16x32_bf16(fa0, fb0, acc[0][0], 0, 0, 0);
        acc[0][1] = __builtin_amdgcn_mfma_f32_16x16x32_bf16(fa0, fb1, acc[0][1], 0, 0, 0);
        acc[1][0] = __builtin_amdgcn_mfma_f32_16x16x32_bf16(fa1, fb0, acc[1][0], 0, 0, 0);
        acc[1][1] = __builtin_amdgcn_mfma_f32_16x16x32_bf16(fa1, fb1, acc[1][1], 0, 0, 0);
    }

    const float bia0 = b_ih[n0 + n_off + lr];
    const float bia1 = b_ih[n0 + n_off + 16 + lr];
    #pragma unroll
    for (int mi = 0; mi < 2; ++mi)
        #pragma unroll
        for (int ni = 0; ni < 2; ++ni) {
            const int n = n0 + n_off + ni * 16 + lr;
            const float bia = ni ? bia1 : bia0;
            #pragma unroll
            for (int q = 0; q < 4; ++q) {
                const int m = m0 + m_off + mi * 16 + lq * 4 + q;
                gi[(size_t)m * G3 + n] = f2bf(acc[mi][ni][q] + bia);
            }
        }
}

// ============================================================================
// K2: recurrence. Cooperative launch ONLY for co-residency; grid.sync()
// replaced by gbar (one per step). Structure otherwise as round-1 (passing).
// ============================================================================
__global__ __launch_bounds__(256, 1) void rec_kernel(
    const unsigned short* __restrict__ gi,
    const float* __restrict__ w_hh, const float* __restrict__ b_hh,
    unsigned short* __restrict__ hb0, unsigned short* __restrict__ hb1,
    float* __restrict__ hf, unsigned int* bar, int chunk, int pbase)
{
    __shared__ __align__(16) unsigned short Wsm[24 * WPAD];  // 48.4 KB
    __shared__ float red[32 * 33];

    const int tid = threadIdx.x;
    const int wg  = blockIdx.x;
    const int g = wg & 1, s = wg >> 1;
    const int b0 = g * 32, j0 = s * 8;

    // ---- load w_hh slice -> LDS bf16 ----
    #pragma unroll 4
    for (int it = 0; it < 24; ++it) {
        const int i   = it * 256 + tid;
        const int row = i >> 8;
        const int c4  = (i & 255) * 4;
        const int gate = row >> 3, u = row & 7;
        const float4 v = *(const float4*)(w_hh + (size_t)(gate * RNN + j0 + u) * RNN + c4);
        unsigned short* dst = &Wsm[row * WPAD + c4];
        dst[0] = f2bf(v.x); dst[1] = f2bf(v.y); dst[2] = f2bf(v.z); dst[3] = f2bf(v.w);
    }

    const int u  = tid & 7;
    const int bl = tid >> 3;
    const int j  = j0 + u;
    const int b  = b0 + bl;
    const float bhr = b_hh[j], bhi = b_hh[RNN + j], bhn = b_hh[2 * RNN + j];

    float h_reg;
    if (chunk == 0) {
        h_reg = 0.f;
        hb0[b * RNN + j] = 0;               // publish initial h (ws is poisoned)
    } else {
        h_reg = hf[b * RNN + j];            // f32 state from previous launch
    }
    gbar(bar, wg, (unsigned)(pbase + 1));   // initial h visible grid-wide

    const int lane = tid & 63, wv = tid >> 6;
    const int mt = wv & 1, ntile = wv >> 1;
    const int lr = lane & 15, lq = lane >> 4;
    const int ar = mt ? (lr < 8 ? 16 + lr : 23) : lr;   // clamp pad rows
    const unsigned short* wrow = Wsm + ar * WPAD;
    const size_t hrow = (size_t)(b0 + ntile * 16 + lr) * RNN;

    for (int t = 0; t < TCH; ++t) {
        const unsigned short* hrd = (t & 1) ? hb1 : hb0;
        unsigned short*       hwr = (t & 1) ? hb0 : hb1;

        const size_t gbase = ((size_t)t * BATCH + b) * G3 + j0 + u;
        const float gir = bf2f(gi[gbase]);
        const float gii = bf2f(gi[gbase + RNN]);
        const float gin = bf2f(gi[gbase + 2 * RNN]);

        f32x4 acc = (f32x4){0.f, 0.f, 0.f, 0.f};
        #pragma unroll 8
        for (int ks = 0; ks < 32; ++ks) {
            const int k = ks * 32 + lq * 8;
            const short8 bfrag = *(const short8*)(hrd + hrow + k);
            const short8 afrag = *(const short8*)(wrow + k);
            acc = __builtin_amdgcn_mfma_f32_16x16x32_bf16(afrag, bfrag, acc, 0, 0, 0);
        }
        #pragma unroll
        for (int q = 0; q < 4; ++q)
            red[(mt * 16 + lq * 4 + q) * 33 + ntile * 16 + lr] = acc[q];
        __syncthreads();

        const float ghr = red[u * 33 + bl];
        const float ghi = red[(8 + u) * 33 + bl];
        const float ghn = red[(16 + u) * 33 + bl];
        const float rr = sigmoidf_(gir + ghr + bhr);
        const float zz = sigmoidf_(gii + ghi + bhi);
        const float nn = tanhf_(gin + rr * (ghn + bhn));
        h_reg = zz * nn + (1.f - zz) * h_reg;
        hwr[b * RNN + j] = f2bf(h_reg);

        gbar(bar, wg, (unsigned)(pbase + 2 + t));   // h visible; guards red[] reuse
    }
    hf[b * RNN + j] = h_reg;
}

// ============================================================================
// K3: out[b,o] = h_last[b,:] . fc_w[o,:] + fc_b[o]
// ============================================================================
__global__ __launch_bounds__(256) void out_kernel(
    const float* __restrict__ hf, const float* __restrict__ fc_w,
    const float* __restrict__ fc_b, float* __restrict__ out)
{
    __shared__ float red[256];
    const int bidx = blockIdx.x, tid = threadIdx.x;
    const int o = tid & 3, seg = tid >> 2;
    const float* hp = hf   + (size_t)bidx * RNN + seg * 16;
    const float* wp = fc_w + (size_t)o * RNN + seg * 16;
    float acc = 0.f;
    #pragma unroll
    for (int i = 0; i < 16; ++i) acc += hp[i] * wp[i];
    red[tid] = acc;
    __syncthreads();
    if (tid < 4) {
        float s = fc_b[tid];
        #pragma unroll 8
        for (int q = 0; q < 64; ++q) s += red[q * 4 + tid];
        out[bidx * 4 + tid] = s;
    }
}

extern "C" void kernel_launch(void* const* d_in, const int* in_sizes, int n_in,
                              void* d_out, int out_size, void* d_ws, size_t ws_size,
                              hipStream_t stream)
{
    const int*   x     = (const int*)d_in[0];
    const float* emb   = (const float*)d_in[1];
    const float* w_ih  = (const float*)d_in[2];
    const float* w_hh  = (const float*)d_in[3];
    const float* b_ih  = (const float*)d_in[4];
    const float* b_hh  = (const float*)d_in[5];
    const float* fc_w  = (const float*)d_in[6];
    const float* fc_b  = (const float*)d_in[7];
    float*       out   = (float*)d_out;

    char* ws = (char*)d_ws;
    unsigned short* gi_buf = (unsigned short*)ws;                      // 50.3 MB
    size_t off = (size_t)TCH * BATCH * G3 * 2;
    unsigned short* hb0 = (unsigned short*)(ws + off); off += BATCH * RNN * 2;
    unsigned short* hb1 = (unsigned short*)(ws + off); off += BATCH * RNN * 2;
    float*          hf  = (float*)(ws + off);          off += BATCH * RNN * 4;
    unsigned int*   bar = (unsigned int*)(ws + off);   // (32*16+16)*4 B

    bar_init<<<dim3(1), dim3(1024), 0, stream>>>(bar);

    for (int c = 0; c < NCHUNK; ++c) {
        const int t0 = c * TCH;
        gi_kernel<<<dim3(128 * 48), dim3(256), 0, stream>>>(x, emb, w_ih, b_ih, gi_buf, t0);
        int cc = c, pb = c * (TCH + 1);
        void* args[9];
        args[0] = (void*)&gi_buf; args[1] = (void*)&w_hh; args[2] = (void*)&b_hh;
        args[3] = (void*)&hb0;    args[4] = (void*)&hb1;  args[5] = (void*)&hf;
        args[6] = (void*)&bar;    args[7] = (void*)&cc;   args[8] = (void*)&pb;
        hipLaunchCooperativeKernel((const void*)rec_kernel, dim3(NWG), dim3(256),
                                   args, 0, stream);
    }
    out_kernel<<<dim3(BATCH), dim3(256), 0, stream>>>(hf, fc_w, fc_b, out);
}

// Round 3
// 3460.732 us; speedup vs baseline: 5.3921x; 2.6223x over previous
//
#include <hip/hip_runtime.h>
#include <hip/hip_bf16.h>

typedef __attribute__((ext_vector_type(8))) short  short8;   // 8 bf16 (4 VGPRs) MFMA frag
typedef __attribute__((ext_vector_type(4))) float  f32x4;    // MFMA accum frag

#define T_TOTAL 512
#define BATCH   64
#define EMB     512
#define RNN     1024
#define G3      3072      // 3*RNN
#define TCH     128       // timesteps per chunk (ws: 128*64*3072*2B = 50.3 MB)
#define NCHUNK  4
#define WPAD    1032      // LDS row stride (shorts) for w_hh slice: 129 x 16B units
#define RPAD    35        // red[] batch stride (floats), breaks 8-way on gate reads
#define NWG     256
#define NCNT    32        // arrival counters, 128B-padded: 8 WGs per counter

// ---- bf16 helpers ----
__device__ __forceinline__ unsigned short f2bf(float f) {
    union { float f; unsigned int u; } v; v.f = f;
    unsigned int r = v.u + 0x7fffu + ((v.u >> 16) & 1u);   // round-nearest-even
    return (unsigned short)(r >> 16);
}
__device__ __forceinline__ float bf2f(unsigned short h) {
    union { unsigned int u; float f; } v; v.u = ((unsigned int)h) << 16;
    return v.f;
}
__device__ __forceinline__ float sigmoidf_(float x) { return 1.f / (1.f + __expf(-x)); }
__device__ __forceinline__ float tanhf_(float x) {
    float ax = fabsf(x);
    float e2 = __expf(-2.f * ax);
    float t  = (1.f - e2) / (1.f + e2);
    return x < 0.f ? -t : t;
}

// ============================================================================
// Grid barrier, pure relaxed agent-scope (sc1) atomics — NO cache-maintenance
// fences. All cross-WG payload (h) is itself written/read with sc1 atomics,
// so the only ordering needed is per-wave vmcnt order:
//   h stores drained by __syncthreads (implicit vmcnt(0)) -> arrival add
//   master: counter loads returned -> flag store
//   spinner: flag load returned -> h loads issued after (program order)
// Counters monotonic across the whole launch sequence (never reset).
// ============================================================================
__device__ __forceinline__ void gbar(unsigned int* bar, int wg, unsigned int ph) {
    __syncthreads();
    if (threadIdx.x == 0) {
        __hip_atomic_fetch_add(&bar[(wg & (NCNT - 1)) * 32], 1u,
                               __ATOMIC_RELAXED, __HIP_MEMORY_SCOPE_AGENT);
        if (wg == 0) {
            for (;;) {
                unsigned int ssum = 0;
                #pragma unroll
                for (int i = 0; i < NCNT; ++i)
                    ssum += __hip_atomic_load(&bar[i * 32], __ATOMIC_RELAXED,
                                              __HIP_MEMORY_SCOPE_AGENT);
                if (ssum >= ph * (unsigned)NWG) break;
                __builtin_amdgcn_s_sleep(1);
            }
            __hip_atomic_store(&bar[NCNT * 32], ph, __ATOMIC_RELAXED,
                               __HIP_MEMORY_SCOPE_AGENT);
        } else {
            while (__hip_atomic_load(&bar[NCNT * 32], __ATOMIC_RELAXED,
                                     __HIP_MEMORY_SCOPE_AGENT) < ph)
                __builtin_amdgcn_s_sleep(1);
        }
    }
    __syncthreads();
}

__global__ void bar_init(unsigned int* bar) {
    for (int i = threadIdx.x; i < NCNT * 32 + 32; i += 256) bar[i] = 0;
}

// ============================================================================
// K1: gi[t,b,:] = emb_table[x[t,b]] @ w_ih^T + b_ih   (one chunk of TCH steps)
// ============================================================================
__global__ __launch_bounds__(256) void gi_kernel(
    const int* __restrict__ x, const float* __restrict__ emb,
    const float* __restrict__ w_ih, const float* __restrict__ b_ih,
    unsigned short* __restrict__ gi, int t0)
{
    __shared__ __align__(16) unsigned short Asm[64 * 40];
    __shared__ __align__(16) unsigned short Bsm[64 * 40];

    const int tid = threadIdx.x;
    const int mt = blockIdx.x & 127;
    const int nt = blockIdx.x >> 7;
    const int m0 = mt * 64, n0 = nt * 64;

    const int r  = tid >> 2;
    const int c8 = (tid & 3) * 8;
    const int xi = x[t0 * BATCH + m0 + r];
    const float* arow = emb  + (size_t)xi * EMB;
    const float* brow = w_ih + (size_t)(n0 + r) * EMB;

    const int lane = tid & 63, wv = tid >> 6;
    const int m_off = (wv & 1) * 32, n_off = (wv >> 1) * 32;
    const int lr = lane & 15, lq = lane >> 4;

    f32x4 acc[2][2];
    #pragma unroll
    for (int i = 0; i < 2; ++i)
        #pragma unroll
        for (int j = 0; j < 2; ++j) acc[i][j] = (f32x4){0.f, 0.f, 0.f, 0.f};

    for (int k0 = 0; k0 < EMB; k0 += 32) {
        const float4 a0 = *(const float4*)(arow + k0 + c8);
        const float4 a1 = *(const float4*)(arow + k0 + c8 + 4);
        const float4 b0 = *(const float4*)(brow + k0 + c8);
        const float4 b1 = *(const float4*)(brow + k0 + c8 + 4);
        __syncthreads();
        short8 av, bv;
        av[0]=f2bf(a0.x); av[1]=f2bf(a0.y); av[2]=f2bf(a0.z); av[3]=f2bf(a0.w);
        av[4]=f2bf(a1.x); av[5]=f2bf(a1.y); av[6]=f2bf(a1.z); av[7]=f2bf(a1.w);
        bv[0]=f2bf(b0.x); bv[1]=f2bf(b0.y); bv[2]=f2bf(b0.z); bv[3]=f2bf(b0.w);
        bv[4]=f2bf(b1.x); bv[5]=f2bf(b1.y); bv[6]=f2bf(b1.z); bv[7]=f2bf(b1.w);
        *(short8*)&Asm[r * 40 + c8] = av;
        *(short8*)&Bsm[r * 40 + c8] = bv;
        __syncthreads();

        const short8 fa0 = *(const short8*)&Asm[(m_off + lr)      * 40 + lq * 8];
        const short8 fa1 = *(const short8*)&Asm[(m_off + 16 + lr) * 40 + lq * 8];
        const short8 fb0 = *(const short8*)&Bsm[(n_off + lr)      * 40 + lq * 8];
        const short8 fb1 = *(const short8*)&Bsm[(n_off + 16 + lr) * 40 + lq * 8];
        acc[0][0] = __builtin_amdgcn_mfma_f32_16x16x32_bf16(fa0, fb0, acc[0][0], 0, 0, 0);
        acc[0][1] = __builtin_amdgcn_mfma_f32_16x16x32_bf16(fa0, fb1, acc[0][1], 0, 0, 0);
        acc[1][0] = __builtin_amdgcn_mfma_f32_16x16x32_bf16(fa1, fb0, acc[1][0], 0, 0, 0);
        acc[1][1] = __builtin_amdgcn_mfma_f32_16x16x32_bf16(fa1, fb1, acc[1][1], 0, 0, 0);
    }

    const float bia0 = b_ih[n0 + n_off + lr];
    const float bia1 = b_ih[n0 + n_off + 16 + lr];
    #pragma unroll
    for (int mi = 0; mi < 2; ++mi)
        #pragma unroll
        for (int ni = 0; ni < 2; ++ni) {
            const int n = n0 + n_off + ni * 16 + lr;
            const float bia = ni ? bia1 : bia0;
            #pragma unroll
            for (int q = 0; q < 4; ++q) {
                const int m = m0 + m_off + mi * 16 + lq * 4 + q;
                gi[(size_t)m * G3 + n] = f2bf(acc[mi][ni][q] + bia);
            }
        }
}

// ============================================================================
// K2: recurrence. WG (g,s): batches b0=g*32..+32, units j0=s*8..+8.
// Waves: (ntile = batch half, kh = K half); each wave computes BOTH m-tiles
// (w rows 0-15, 16-23) -> unique h reads (64 KB/WG/step via sc1 from MALL).
// h stores: packed u32 sc1 atomics. One gbar per step. Gi prefetched ahead.
// ============================================================================
__global__ __launch_bounds__(256, 1) void rec_kernel(
    const unsigned short* __restrict__ gi,
    const float* __restrict__ w_hh, const float* __restrict__ b_hh,
    unsigned short* __restrict__ hb0, unsigned short* __restrict__ hb1,
    float* __restrict__ hf, unsigned int* bar, int chunk, int pbase)
{
    __shared__ __align__(16) unsigned short Wsm[24 * WPAD];  // 49.5 KB
    __shared__ float red[2][24][RPAD];                       // K-half partials

    const int tid = threadIdx.x;
    const int wg  = blockIdx.x;
    const int g = wg & 1, s = wg >> 1;
    const int b0 = g * 32, j0 = s * 8;

    // ---- stage w_hh slice -> LDS bf16 (rows: [gate*8+u][k]) ----
    #pragma unroll 4
    for (int it = 0; it < 24; ++it) {
        const int i   = it * 256 + tid;
        const int row = i >> 8;
        const int c4  = (i & 255) * 4;
        const int gate = row >> 3, uu = row & 7;
        const float4 v = *(const float4*)(w_hh + (size_t)(gate * RNN + j0 + uu) * RNN + c4);
        unsigned short* dst = &Wsm[row * WPAD + c4];
        dst[0] = f2bf(v.x); dst[1] = f2bf(v.y); dst[2] = f2bf(v.z); dst[3] = f2bf(v.w);
    }

    const int u  = tid & 7;
    const int bl = tid >> 3;
    const int j  = j0 + u;
    const int b  = b0 + bl;
    const float bhr = b_hh[j], bhi = b_hh[RNN + j], bhn = b_hh[2 * RNN + j];

    float h_reg;
    if (chunk == 0) {
        h_reg = 0.f;
        if ((u & 1) == 0)
            __hip_atomic_store((unsigned int*)&hb0[b * RNN + j], 0u,
                               __ATOMIC_RELAXED, __HIP_MEMORY_SCOPE_AGENT);
    } else {
        h_reg = hf[b * RNN + j];            // f32 state from previous launch
    }
    gbar(bar, wg, (unsigned)(pbase + 1));   // initial h visible grid-wide

    // ---- MFMA identity: wave = (ntile, kh), both m-tiles per wave ----
    const int lane = tid & 63, wv = tid >> 6;
    const int ntile = wv & 1, kh = wv >> 1;
    const int lr = lane & 15, lq = lane >> 4;
    const unsigned short* wrow0 = Wsm + lr * WPAD;                 // w rows 0-15
    const unsigned short* wrow1 = Wsm + (16 + (lr & 7)) * WPAD;    // w rows 16-23 (clamped)
    const size_t hrow = (size_t)(b0 + ntile * 16 + lr) * RNN;
    const int kbase = kh * 512 + lq * 8;

    // gi prefetch for t=0
    size_t gbase = (size_t)b * G3 + j0 + u;
    float gir = bf2f(gi[gbase]);
    float gii = bf2f(gi[gbase + RNN]);
    float gin = bf2f(gi[gbase + 2 * RNN]);

    for (int t = 0; t < TCH; ++t) {
        const unsigned short* hrd = (t & 1) ? hb1 : hb0;
        unsigned short*       hwr = (t & 1) ? hb0 : hb1;

        f32x4 acc0 = (f32x4){0.f, 0.f, 0.f, 0.f};
        f32x4 acc1 = (f32x4){0.f, 0.f, 0.f, 0.f};
        const unsigned long long* hp = (const unsigned long long*)(hrd + hrow + kbase);
        #pragma unroll 8
        for (int ks = 0; ks < 16; ++ks) {
            union { unsigned long long q[2]; short8 s8; } hbv;
            hbv.q[0] = __hip_atomic_load(hp + ks * 8,     __ATOMIC_RELAXED,
                                         __HIP_MEMORY_SCOPE_AGENT);
            hbv.q[1] = __hip_atomic_load(hp + ks * 8 + 1, __ATOMIC_RELAXED,
                                         __HIP_MEMORY_SCOPE_AGENT);
            const int k = ks * 32;
            const short8 a0 = *(const short8*)(wrow0 + kbase + k);
            const short8 a1 = *(const short8*)(wrow1 + kbase + k);
            acc0 = __builtin_amdgcn_mfma_f32_16x16x32_bf16(a0, hbv.s8, acc0, 0, 0, 0);
            acc1 = __builtin_amdgcn_mfma_f32_16x16x32_bf16(a1, hbv.s8, acc1, 0, 0, 0);
        }
        #pragma unroll
        for (int q = 0; q < 4; ++q)
            red[kh][lq * 4 + q][ntile * 16 + lr] = acc0[q];
        if (lq < 2) {
            #pragma unroll
            for (int q = 0; q < 4; ++q)
                red[kh][16 + lq * 4 + q][ntile * 16 + lr] = acc1[q];
        }
        __syncthreads();

        const float ghr = red[0][u][bl]      + red[1][u][bl];
        const float ghi = red[0][8 + u][bl]  + red[1][8 + u][bl];
        const float ghn = red[0][16 + u][bl] + red[1][16 + u][bl];
        const float rr = sigmoidf_(gir + ghr + bhr);
        const float zz = sigmoidf_(gii + ghi + bhi);
        const float nn = tanhf_(gin + rr * (ghn + bhn));
        h_reg = zz * nn + (1.f - zz) * h_reg;

        // packed pair store (u, u^1 share one dword), write-through sc1
        unsigned int hv = (unsigned int)f2bf(h_reg);
        unsigned int ov = __shfl_xor((int)hv, 1);
        if ((u & 1) == 0)
            __hip_atomic_store((unsigned int*)&hwr[b * RNN + j],
                               hv | (ov << 16), __ATOMIC_RELAXED,
                               __HIP_MEMORY_SCOPE_AGENT);

        // prefetch gi(t+1) before the barrier (overlaps spin latency)
        const int tn = (t + 1 < TCH) ? t + 1 : t;
        gbase = ((size_t)tn * BATCH + b) * G3 + j0 + u;
        gir = bf2f(gi[gbase]);
        gii = bf2f(gi[gbase + RNN]);
        gin = bf2f(gi[gbase + 2 * RNN]);

        gbar(bar, wg, (unsigned)(pbase + 2 + t));   // h visible; guards red[] reuse
    }
    hf[b * RNN + j] = h_reg;
}

// ============================================================================
// K3: out[b,o] = h_last[b,:] . fc_w[o,:] + fc_b[o]
// ============================================================================
__global__ __launch_bounds__(256) void out_kernel(
    const float* __restrict__ hf, const float* __restrict__ fc_w,
    const float* __restrict__ fc_b, float* __restrict__ out)
{
    __shared__ float red[256];
    const int bidx = blockIdx.x, tid = threadIdx.x;
    const int o = tid & 3, seg = tid >> 2;
    const float* hp = hf   + (size_t)bidx * RNN + seg * 16;
    const float* wp = fc_w + (size_t)o * RNN + seg * 16;
    float acc = 0.f;
    #pragma unroll
    for (int i = 0; i < 16; ++i) acc += hp[i] * wp[i];
    red[tid] = acc;
    __syncthreads();
    if (tid < 4) {
        float sv = fc_b[tid];
        #pragma unroll 8
        for (int q = 0; q < 64; ++q) sv += red[q * 4 + tid];
        out[bidx * 4 + tid] = sv;
    }
}

extern "C" void kernel_launch(void* const* d_in, const int* in_sizes, int n_in,
                              void* d_out, int out_size, void* d_ws, size_t ws_size,
                              hipStream_t stream)
{
    const int*   x     = (const int*)d_in[0];
    const float* emb   = (const float*)d_in[1];
    const float* w_ih  = (const float*)d_in[2];
    const float* w_hh  = (const float*)d_in[3];
    const float* b_ih  = (const float*)d_in[4];
    const float* b_hh  = (const float*)d_in[5];
    const float* fc_w  = (const float*)d_in[6];
    const float* fc_b  = (const float*)d_in[7];
    float*       out   = (float*)d_out;

    char* ws = (char*)d_ws;
    unsigned short* gi_buf = (unsigned short*)ws;                      // 50.3 MB
    size_t off = (size_t)TCH * BATCH * G3 * 2;
    unsigned short* hb0 = (unsigned short*)(ws + off); off += BATCH * RNN * 2;
    unsigned short* hb1 = (unsigned short*)(ws + off); off += BATCH * RNN * 2;
    float*          hf  = (float*)(ws + off);          off += BATCH * RNN * 4;
    unsigned int*   bar = (unsigned int*)(ws + off);   // (32*32+32)*4 B

    bar_init<<<dim3(1), dim3(256), 0, stream>>>(bar);

    for (int c = 0; c < NCHUNK; ++c) {
        const int t0 = c * TCH;
        gi_kernel<<<dim3(128 * 48), dim3(256), 0, stream>>>(x, emb, w_ih, b_ih, gi_buf, t0);
        int cc = c, pb = c * (TCH + 1);
        void* args[9];
        args[0] = (void*)&gi_buf; args[1] = (void*)&w_hh; args[2] = (void*)&b_hh;
        args[3] = (void*)&hb0;    args[4] = (void*)&hb1;  args[5] = (void*)&hf;
        args[6] = (void*)&bar;    args[7] = (void*)&cc;   args[8] = (void*)&pb;
        hipLaunchCooperativeKernel((const void*)rec_kernel, dim3(NWG), dim3(256),
                                   args, 0, stream);
    }
    out_kernel<<<dim3(BATCH), dim3(256), 0, stream>>>(hf, fc_w, fc_b, out);
}